// Round 1
// baseline (6089.882 us; speedup 1.0000x reference)
//
#include <hip/hip_runtime.h>
#include <hip/hip_bf16.h>

// TreeLSTM forward, fp32 correctness-first implementation.
// Topology (compile-time): 16 perfect ternary trees, depth 6, leaves-first level-major.
// off[l] for l=0..5: {5808,5760,5616,5184,3888,0}; N_NODES=5824.
// All large transients live in d_out (scratch until final decoder GEMMs);
// only x/h/c (32MB) live in d_ws.

namespace {

constexpr int NN = 5824;
constexpr int ED = 352;

__device__ __forceinline__ float sigmoidf_(float x) { return 1.f / (1.f + expf(-x)); }

// ---------------- generic tiled GEMM: C = alpha * A @ op(B) [+bias] [+C] [relu] ----------
// A: [M,K] row-major (lda). BT: B stored [N,K] (ldb = row stride) -> C = A@B^T.
// !BT: B stored [K,N] (ldb). Batched via blockIdx.z: off = (z/nh)*s1 + (z%nh)*s2.
template <bool BT, bool ACCUM, bool RELU>
__global__ __launch_bounds__(256) void gemm_k(
    const float* __restrict__ A, const float* __restrict__ B, float* __restrict__ C,
    const float* __restrict__ bias, int M, int N, int K, int lda, int ldb, int ldc,
    float alpha, long long sA1, long long sA2, long long sB1, long long sB2,
    long long sC1, long long sC2, int nh) {
  const int bz = blockIdx.z;
  const int b1 = bz / nh, b2 = bz - b1 * nh;
  A += b1 * sA1 + b2 * sA2;
  B += b1 * sB1 + b2 * sB2;
  C += b1 * sC1 + b2 * sC2;
  const int bm = blockIdx.y * 64;
  const int bn = blockIdx.x * 64;
  __shared__ float As[16][65];
  __shared__ float Bs[16][65];
  const int tid = threadIdx.x;
  const int lr = tid >> 2;          // 0..63
  const int lc = (tid & 3) << 2;    // 0,4,8,12
  const int tm = (tid >> 4) << 2;   // 0..60
  const int tn = (tid & 15) << 2;   // 0..60
  float acc[4][4] = {};

  for (int k0 = 0; k0 < K; k0 += 16) {  // all K in this problem are multiples of 16
    {
      int row = bm + lr;
      float4 v = {0.f, 0.f, 0.f, 0.f};
      if (row < M) v = *reinterpret_cast<const float4*>(A + (long long)row * lda + k0 + lc);
      As[lc + 0][lr] = v.x; As[lc + 1][lr] = v.y; As[lc + 2][lr] = v.z; As[lc + 3][lr] = v.w;
    }
    if (BT) {
      int row = bn + lr;
      float4 v = {0.f, 0.f, 0.f, 0.f};
      if (row < N) v = *reinterpret_cast<const float4*>(B + (long long)row * ldb + k0 + lc);
      Bs[lc + 0][lr] = v.x; Bs[lc + 1][lr] = v.y; Bs[lc + 2][lr] = v.z; Bs[lc + 3][lr] = v.w;
    } else {
      int kr = tid >> 4;           // 0..15
      int cc = (tid & 15) << 2;    // 0..60
      int col = bn + cc;
      const float* p = B + (long long)(k0 + kr) * ldb + col;
      float4 v = {0.f, 0.f, 0.f, 0.f};
      if (col + 3 < N) {
        v = *reinterpret_cast<const float4*>(p);
      } else {
        if (col     < N) v.x = p[0];
        if (col + 1 < N) v.y = p[1];
        if (col + 2 < N) v.z = p[2];
        if (col + 3 < N) v.w = p[3];
      }
      Bs[kr][cc + 0] = v.x; Bs[kr][cc + 1] = v.y; Bs[kr][cc + 2] = v.z; Bs[kr][cc + 3] = v.w;
    }
    __syncthreads();
#pragma unroll
    for (int kk = 0; kk < 16; ++kk) {
      float a0 = As[kk][tm + 0], a1 = As[kk][tm + 1], a2 = As[kk][tm + 2], a3 = As[kk][tm + 3];
      float b0 = Bs[kk][tn + 0], b1v = Bs[kk][tn + 1], b2v = Bs[kk][tn + 2], b3 = Bs[kk][tn + 3];
      acc[0][0] += a0 * b0; acc[0][1] += a0 * b1v; acc[0][2] += a0 * b2v; acc[0][3] += a0 * b3;
      acc[1][0] += a1 * b0; acc[1][1] += a1 * b1v; acc[1][2] += a1 * b2v; acc[1][3] += a1 * b3;
      acc[2][0] += a2 * b0; acc[2][1] += a2 * b1v; acc[2][2] += a2 * b2v; acc[2][3] += a2 * b3;
      acc[3][0] += a3 * b0; acc[3][1] += a3 * b1v; acc[3][2] += a3 * b2v; acc[3][3] += a3 * b3;
    }
    __syncthreads();
  }
#pragma unroll
  for (int i = 0; i < 4; ++i) {
    int row = bm + tm + i;
    if (row >= M) continue;
#pragma unroll
    for (int j = 0; j < 4; ++j) {
      int col = bn + tn + j;
      if (col >= N) continue;
      float v = alpha * acc[i][j];
      if (bias) v += bias[col];
      long long idx = (long long)row * ldc + col;
      if (ACCUM) v += C[idx];
      if (RELU) v = fmaxf(v, 0.f);
      C[idx] = v;
    }
  }
}

static void gemm(hipStream_t st, const float* A, const float* B, float* C, const float* bias,
                 int M, int N, int K, int lda, int ldb, int ldc, float alpha,
                 bool BT, bool accum, bool relu, int batches = 1,
                 long long sA1 = 0, long long sA2 = 0, long long sB1 = 0, long long sB2 = 0,
                 long long sC1 = 0, long long sC2 = 0, int nh = 1) {
  dim3 g((N + 63) / 64, (M + 63) / 64, batches), b(256);
#define GL(BT_, AC_, RL_)                                                        \
  gemm_k<BT_, AC_, RL_><<<g, b, 0, st>>>(A, B, C, bias, M, N, K, lda, ldb, ldc, \
                                         alpha, sA1, sA2, sB1, sB2, sC1, sC2, nh)
  if (BT) {
    if (accum)      GL(true, true, false);
    else if (relu)  GL(true, false, true);
    else            GL(true, false, false);
  } else {
    GL(false, false, false);
  }
#undef GL
}

// ---------------- embedding gather + concat + time-pos + mask ----------------
__global__ __launch_bounds__(256) void embed_k(
    const int* __restrict__ uid, const int* __restrict__ pid, const int* __restrict__ cid,
    const int* __restrict__ gid, const int* __restrict__ tmid, const int* __restrict__ mask,
    const float* __restrict__ ue, const float* __restrict__ pe, const float* __restrict__ ce,
    const float* __restrict__ ge, const float* __restrict__ tp, float* __restrict__ x) {
  int e = blockIdx.x * 256 + threadIdx.x;
  if (e >= NN * ED) return;
  int n = e / ED, j = e - n * ED;
  int mi = mask[n];
  float fm = (float)mi;
  float v;
  if (j < 128)      v = ue[(long long)(uid[n] * mi) * 128 + j];
  else if (j < 256) v = pe[(long long)(pid[n] * mi) * 128 + (j - 128)];
  else if (j < 288) v = ce[(long long)(cid[n] * mi) * 32 + (j - 256)];
  else              v = ge[(long long)(gid[n] * mi) * 64 + (j - 288)];
  v += 0.5f * tp[(long long)(tmid[n] * mi) * ED + j];
  x[e] = v * fm;
}

// ---------------- gather children h/c into [m, 3*512] mailboxes ----------------
__global__ __launch_bounds__(256) void gather_k(
    const float* __restrict__ h, const float* __restrict__ c, float* __restrict__ hch,
    float* __restrict__ cch, int m, int cbase, int tl) {
  int e = blockIdx.x * 256 + threadIdx.x;
  if (e >= m * 1536) return;
  int r = e / 1536, rem = e - r * 1536;
  int k = rem >> 9, d = rem & 511;
  int t = r / tl, p = r - t * tl;
  int child = cbase + t * (3 * tl) + 3 * p + k;
  hch[e] = h[(long long)child * 512 + d];
  cch[e] = c[(long long)child * 512 + d];
}

// ---------------- forget gates + c_red = sum_k sigmoid(Wx + Ufh_k + b_f) * c_ch_k ----------
__global__ __launch_bounds__(256) void fcred_k(
    const float* __restrict__ wx, const float* __restrict__ ufh, const float* __restrict__ bf,
    const float* __restrict__ cch, float* __restrict__ cred, int m) {
  int e = blockIdx.x * 256 + threadIdx.x;
  if (e >= m * 512) return;
  int r = e >> 9, d = e & 511;
  float w = wx[e] + bf[d];
  long long base = (long long)r * 1536;
  float acc = 0.f;
#pragma unroll
  for (int k = 0; k < 3; ++k) {
    float f = sigmoidf_(w + ufh[base + k * 512 + d]);
    acc += f * cch[base + k * 512 + d];
  }
  cred[e] = acc;
}

// ---------------- iou -> (h,c) update; cred==nullptr for leaves ----------------
__global__ __launch_bounds__(256) void combine_k(
    const float* __restrict__ iou, const float* __restrict__ cred, float* __restrict__ h,
    float* __restrict__ c, int off, int m) {
  int e = blockIdx.x * 256 + threadIdx.x;
  if (e >= m * 512) return;
  int r = e >> 9, d = e & 511;
  long long b = (long long)r * 1536;
  float iv = iou[b + d], ov = iou[b + 512 + d], uv = iou[b + 1024 + d];
  float cr = cred ? cred[e] : 0.f;
  float cn = sigmoidf_(iv) * tanhf(uv) + cr;
  float hn = sigmoidf_(ov) * tanhf(cn);
  h[(long long)(off + r) * 512 + d] = hn;
  c[(long long)(off + r) * 512 + d] = cn;
}

// ---------------- LayerNorm over width 512: out = LN(a+b)*w + bias ----------------
__global__ __launch_bounds__(256) void ln_k(
    const float* a, const float* b, const float* __restrict__ w,
    const float* __restrict__ bias, float* out) {
  int r = blockIdx.x, t = threadIdx.x;
  long long base = (long long)r * 512;
  float v0 = a[base + t] + b[base + t];
  float v1 = a[base + 256 + t] + b[base + 256 + t];
  __shared__ float s1[256], s2[256];
  s1[t] = v0 + v1;
  s2[t] = v0 * v0 + v1 * v1;
  __syncthreads();
  for (int s = 128; s > 0; s >>= 1) {
    if (t < s) { s1[t] += s1[t + s]; s2[t] += s2[t + s]; }
    __syncthreads();
  }
  float mu = s1[0] * (1.f / 512.f);
  float var = s2[0] * (1.f / 512.f) - mu * mu;
  float rs = rsqrtf(var + 1e-5f);
  out[base + t] = (v0 - mu) * rs * w[t] + bias[t];
  out[base + 256 + t] = (v1 - mu) * rs * w[256 + t] + bias[256 + t];
}

// ---------------- row softmax, in place; rows of length S ----------------
__global__ __launch_bounds__(256) void softmax_k(float* __restrict__ p, int S) {
  long long r = blockIdx.x;
  float* row = p + r * S;
  int t = threadIdx.x;
  __shared__ float sh[256];
  float mx = -3.4e38f;
  for (int j = t; j < S; j += 256) mx = fmaxf(mx, row[j]);
  sh[t] = mx;
  __syncthreads();
  for (int s = 128; s > 0; s >>= 1) {
    if (t < s) sh[t] = fmaxf(sh[t], sh[t + s]);
    __syncthreads();
  }
  mx = sh[0];
  __syncthreads();
  float sum = 0.f;
  for (int j = t; j < S; j += 256) {
    float e = expf(row[j] - mx);
    row[j] = e;
    sum += e;
  }
  sh[t] = sum;
  __syncthreads();
  for (int s = 128; s > 0; s >>= 1) {
    if (t < s) sh[t] += sh[t + s];
    __syncthreads();
  }
  float inv = 1.f / sh[0];
  for (int j = t; j < S; j += 256) row[j] *= inv;
}

}  // namespace

extern "C" void kernel_launch(void* const* d_in, const int* in_sizes, int n_in,
                              void* d_out, int out_size, void* d_ws, size_t ws_size,
                              hipStream_t stream) {
  const int* uid  = (const int*)d_in[0];
  const int* pid  = (const int*)d_in[1];
  const int* cid  = (const int*)d_in[2];
  const int* gid  = (const int*)d_in[3];
  const int* tmid = (const int*)d_in[4];
  const int* mask = (const int*)d_in[5];
  const float* ue = (const float*)d_in[6];
  const float* pe = (const float*)d_in[7];
  const float* ce = (const float*)d_in[8];
  const float* ge = (const float*)d_in[9];
  const float* tp = (const float*)d_in[10];
  const float* W_iou = (const float*)d_in[11];
  const float* U_iou = (const float*)d_in[12];
  const float* b_iou = (const float*)d_in[13];
  const float* W_f = (const float*)d_in[14];
  const float* U_f = (const float*)d_in[15];
  const float* b_f = (const float*)d_in[16];
  const float* qkv_w = (const float*)d_in[17];
  const float* qkv_b = (const float*)d_in[18];
  const float* out_w = (const float*)d_in[19];
  const float* out_b = (const float*)d_in[20];
  const float* ln1_w = (const float*)d_in[21];
  const float* ln1_b = (const float*)d_in[22];
  const float* ff1_w = (const float*)d_in[23];
  const float* ff1_b = (const float*)d_in[24];
  const float* ff2_w = (const float*)d_in[25];
  const float* ff2_b = (const float*)d_in[26];
  const float* ln2_w = (const float*)d_in[27];
  const float* ln2_b = (const float*)d_in[28];
  const float* dpw = (const float*)d_in[29];
  const float* dpb = (const float*)d_in[30];
  const float* dcw = (const float*)d_in[31];
  const float* dcb = (const float*)d_in[32];
  const float* dgw = (const float*)d_in[33];
  const float* dgb = (const float*)d_in[34];

  // persistent state in d_ws (32MB): x [5824,352], h [5824,512], c [5824,512]
  float* ws = (float*)d_ws;
  float* X = ws;
  float* H = ws + 2050048LL;
  float* Cc = ws + 5031936LL;

  // transients carved out of d_out (dead until decoders at the end)
  float* ob   = (float*)d_out;
  float* SC   = ob;                  // 6*1296*1296 = 10,077,696
  float* QKV  = ob + 10077696LL;     // 3888*1536
  float* IOU  = ob + 16049664LL;     // 3888*1536 (leaf) / m*1536 (levels)
  float* HCH  = ob + 22021632LL;     // 1296*1536 (= transformer X, [3m,512])
  float* CCH  = ob + 24012288LL;
  float* UFH  = ob + 26002944LL;
  float* ATTO = ob + 27993600LL;     // [3m,512]
  float* XB   = ob + 29984256LL;
  float* XC   = ob + 31974912LL;
  float* WX   = ob + 33965568LL;     // [m,512]
  float* CRED = ob + 34629120LL;     // [m,512]  (end 35,292,672 <= 36,830,976)

  // 1) embeddings
  embed_k<<<(NN * ED + 255) / 256, 256, 0, stream>>>(uid, pid, cid, gid, tmid, mask,
                                                     ue, pe, ce, ge, tp, X);

  // 2) leaves: iou = x[0:3888] @ W_iou^T (no bias); c=sig(i)tanh(u); h=sig(o)tanh(c)
  gemm(stream, X, W_iou, IOU, nullptr, 3888, 1536, 352, 352, 352, 1536, 1.f, true, false, false);
  combine_k<<<(3888 * 512 + 255) / 256, 256, 0, stream>>>(IOU, nullptr, H, Cc, 0, 3888);

  static const int OFFL[6] = {5808, 5760, 5616, 5184, 3888, 0};
  int tl = 81;  // 3^l, starting at l=4
  for (int l = 4; l >= 0; --l, tl /= 3) {
    int m = 16 * tl;
    int off = OFFL[l];
    int cbase = OFFL[l + 1];
    const float* xl = X + (long long)off * ED;
    int T = 3 * m;

    gather_k<<<(m * 1536 + 255) / 256, 256, 0, stream>>>(H, Cc, HCH, CCH, m, cbase, tl);
    // forget gates (use original h_ch before transformer overwrites HCH)
    gemm(stream, xl, W_f, WX, nullptr, m, 512, 352, 352, 352, 512, 1.f, true, false, false);
    gemm(stream, HCH, U_f, UFH, nullptr, m, 1536, 1536, 1536, 1536, 1536, 1.f, true, false, false);
    fcred_k<<<(m * 512 + 255) / 256, 256, 0, stream>>>(WX, UFH, b_f, CCH, CRED, m);

    // transformer over [S=m, B=3, H=512]; X lives in HCH ([3m,512] token-major)
    for (int i = 0; i < 2; ++i) {
      gemm(stream, HCH, qkv_w + (long long)i * 1536 * 512, QKV, qkv_b + i * 1536,
           T, 1536, 512, 512, 512, 1536, 1.f, true, false, false);
      // scores[b,h] = (1/16) Q @ K^T; Q/K views of QKV with lda 3*1536, offsets b*1536+h*256
      gemm(stream, QKV, QKV + 512, SC, nullptr, m, m, 256, 4608, 4608, m, 0.0625f,
           true, false, false, 6, 1536, 256, 1536, 256, 2LL * m * m, (long long)m * m, 2);
      softmax_k<<<6 * m, 256, 0, stream>>>(SC, m);
      // attn @ V -> ATTO[(s*3+b)*512 + h*256 + d]
      gemm(stream, SC, QKV + 1024, ATTO, nullptr, m, 256, m, m, 4608, 1536, 1.f,
           false, false, false, 6, 2LL * m * m, (long long)m * m, 1536, 256, 512, 256, 2);
      gemm(stream, ATTO, out_w + (long long)i * 262144, XB, out_b + i * 512,
           T, 512, 512, 512, 512, 512, 1.f, true, false, false);
      ln_k<<<T, 256, 0, stream>>>(HCH, XB, ln1_w + i * 512, ln1_b + i * 512, HCH);
      gemm(stream, HCH, ff1_w + (long long)i * 262144, XC, ff1_b + i * 512,
           T, 512, 512, 512, 512, 512, 1.f, true, false, true);
      gemm(stream, XC, ff2_w + (long long)i * 262144, XB, ff2_b + i * 512,
           T, 512, 512, 512, 512, 512, 1.f, true, false, false);
      ln_k<<<T, 256, 0, stream>>>(HCH, XB, ln2_w + i * 512, ln2_b + i * 512, HCH);
    }

    // iou = xl@W_iou^T + b_iou + h_att@U_iou^T  (h_att == HCH viewed [m,1536])
    gemm(stream, xl, W_iou, IOU, b_iou, m, 1536, 352, 352, 352, 1536, 1.f, true, false, false);
    gemm(stream, HCH, U_iou, IOU, nullptr, m, 1536, 1536, 1536, 1536, 1536, 1.f, true, true, false);
    combine_k<<<(m * 512 + 255) / 256, 256, 0, stream>>>(IOU, CRED, H, Cc, off, m);
  }

  // 3) decoders, overwrite d_out: y_poi [5824,5000], y_cat [5824,300], y_coo [5824,1024]
  gemm(stream, H, dpw, ob, dpb, NN, 5000, 512, 512, 512, 5000, 1.f, true, false, false);
  gemm(stream, H, dcw, ob + 29120000LL, dcb, NN, 300, 512, 512, 512, 300, 1.f, true, false, false);
  gemm(stream, H, dgw, ob + 30867200LL, dgb, NN, 1024, 512, 512, 512, 1024, 1.f, true, false, false);
}

// Round 3
// 3492.619 us; speedup vs baseline: 1.7436x; 1.7436x over previous
//
#include <hip/hip_runtime.h>
#include <hip/hip_bf16.h>

// TreeLSTM forward, round 3: bf16 MFMA GEMMs with split-precision (hi/lo bf16)
// activations on error-critical paths; fp32 accumulate everywhere.
// Topology: 16 perfect ternary trees, depth 6; off[l] l=0..5: {5808,5760,5616,5184,3888,0}.

namespace {

constexpr int NN = 5824;
constexpr int ED = 352;

typedef __bf16 bf16;
typedef short s16x8 __attribute__((ext_vector_type(8)));
typedef float f32x4 __attribute__((ext_vector_type(4)));

__device__ __forceinline__ float sigmoidf_(float x) { return 1.f / (1.f + expf(-x)); }

__device__ __forceinline__ void gload_lds16(const void* g, void* s) {
  __builtin_amdgcn_global_load_lds(
      (const __attribute__((address_space(1))) unsigned int*)g,
      (__attribute__((address_space(3))) unsigned int*)s, 16, 0, 0);
}

// ---------------- bf16 MFMA GEMM: C = alpha * A @ B^T + bias [+Cacc] [relu] ------------
// A: [M,K] bf16 row-major. B: [N,K] bf16 row-major. 128x128 tile, BK=32.
// OTYPE 0: write fp32 Cp. OTYPE 1: write bf16 Cp. OTYPE 2: write bf16 pair (Cp=hi, Clo).
// ACCUM: v += Cacc[idx] (fp32 source, same ldc/strides).
template <int OTYPE, bool ACCUM, bool RELU>
__global__ __launch_bounds__(256) void bgemm_k(
    const bf16* __restrict__ A, const bf16* __restrict__ B, void* __restrict__ Cp,
    bf16* __restrict__ Clo, const float* __restrict__ Cacc, const float* __restrict__ bias,
    int M, int N, int K, int lda, int ldb, int ldc, float alpha,
    long long sA1, long long sA2, long long sB1, long long sB2,
    long long sC1, long long sC2, int nh) {
  const int bz = blockIdx.z;
  const int b1 = bz / nh, b2 = bz - b1 * nh;
  A += (long long)b1 * sA1 + (long long)b2 * sA2;
  B += (long long)b1 * sB1 + (long long)b2 * sB2;
  const long long coff = (long long)b1 * sC1 + (long long)b2 * sC2;
  const int bm = blockIdx.y * 128, bn = blockIdx.x * 128;
  __shared__ bf16 As[128 * 32];
  __shared__ bf16 Bs[128 * 32];
  const int tid = threadIdx.x;
  const int l = tid & 63;
  const int wr = ((tid >> 7) & 1) * 64;
  const int wc = ((tid >> 6) & 1) * 64;
  f32x4 acc[4][4];
#pragma unroll
  for (int i = 0; i < 4; ++i)
#pragma unroll
    for (int j = 0; j < 4; ++j) acc[i][j] = (f32x4){0.f, 0.f, 0.f, 0.f};

  for (int k0 = 0; k0 < K; k0 += 32) {
#pragma unroll
    for (int r = 0; r < 2; ++r) {
      int idx = r * 256 + tid;
      int row = idx >> 2, cs = idx & 3;
      int cg = cs ^ (row & 3);
      int ra = bm + row; if (ra > M - 1) ra = M - 1;
      int rb = bn + row; if (rb > N - 1) rb = N - 1;
      gload_lds16(A + (long long)ra * lda + k0 + cg * 8, As + idx * 8);
      gload_lds16(B + (long long)rb * ldb + k0 + cg * 8, Bs + idx * 8);
    }
    __syncthreads();
    s16x8 af[4], bfr[4];
#pragma unroll
    for (int mi = 0; mi < 4; ++mi) {
      int row = wr + mi * 16 + (l & 15);
      int ch = ((l >> 4) ^ row) & 3;
      af[mi] = *reinterpret_cast<const s16x8*>(As + row * 32 + ch * 8);
    }
#pragma unroll
    for (int ni = 0; ni < 4; ++ni) {
      int row = wc + ni * 16 + (l & 15);
      int ch = ((l >> 4) ^ row) & 3;
      bfr[ni] = *reinterpret_cast<const s16x8*>(Bs + row * 32 + ch * 8);
    }
#pragma unroll
    for (int mi = 0; mi < 4; ++mi)
#pragma unroll
      for (int ni = 0; ni < 4; ++ni)
        acc[mi][ni] =
            __builtin_amdgcn_mfma_f32_16x16x32_bf16(af[mi], bfr[ni], acc[mi][ni], 0, 0, 0);
    __syncthreads();
  }

  const int lc = l & 15, lr4 = (l >> 4) * 4;
#pragma unroll
  for (int mi = 0; mi < 4; ++mi) {
#pragma unroll
    for (int j = 0; j < 4; ++j) {
      int r = bm + wr + mi * 16 + lr4 + j;
      if (r >= M) continue;
#pragma unroll
      for (int ni = 0; ni < 4; ++ni) {
        int c = bn + wc + ni * 16 + lc;
        if (c >= N) continue;
        float v = alpha * acc[mi][ni][j];
        if (bias) v += bias[c];
        long long idx = coff + (long long)r * ldc + c;
        if (ACCUM) v += Cacc[idx];
        if (RELU) v = fmaxf(v, 0.f);
        if (OTYPE == 0) {
          ((float*)Cp)[idx] = v;
        } else if (OTYPE == 1) {
          ((bf16*)Cp)[idx] = (bf16)v;
        } else {
          bf16 hv = (bf16)v;
          ((bf16*)Cp)[idx] = hv;
          Clo[idx] = (bf16)(v - (float)hv);
        }
      }
    }
  }
}

static void bgemm(hipStream_t st, int ot, bool ac, const bf16* A, const bf16* B, void* Cp,
                  bf16* Clo, const float* Cacc, const float* bias, int M, int N, int K,
                  int lda, int ldb, int ldc, float alpha, int batches = 1,
                  long long sA1 = 0, long long sA2 = 0, long long sB1 = 0, long long sB2 = 0,
                  long long sC1 = 0, long long sC2 = 0, int nh = 1) {
  dim3 g((N + 127) / 128, (M + 127) / 128, batches), b(256);
#define BGL(OT_, AC_, RL_)                                                              \
  bgemm_k<OT_, AC_, RL_><<<g, b, 0, st>>>(A, B, Cp, Clo, Cacc, bias, M, N, K, lda, ldb, \
                                          ldc, alpha, sA1, sA2, sB1, sB2, sC1, sC2, nh)
  if (ot == 0 && !ac)      BGL(0, false, false);
  else if (ot == 0 && ac)  BGL(0, true, false);
  else if (ot == 1 && !ac) BGL(1, false, false);
  else if (ot == 1 && ac)  BGL(1, true, false);
  else                     BGL(2, true, true);   // ot==2: accum + relu + pair out (ff1 p2)
#undef BGL
}

// ---------------- fp32 -> bf16 conversion (n multiple of 8) ----------------
__global__ __launch_bounds__(256) void cvt8_k(const float* __restrict__ s,
                                              bf16* __restrict__ d, int n8) {
  int i = blockIdx.x * 256 + threadIdx.x;
  if (i >= n8) return;
  const float4* p = reinterpret_cast<const float4*>(s + (long long)i * 8);
  float4 a = p[0], b = p[1];
  bf16 o[8] = {(bf16)a.x, (bf16)a.y, (bf16)a.z, (bf16)a.w,
               (bf16)b.x, (bf16)b.y, (bf16)b.z, (bf16)b.w};
  *reinterpret_cast<s16x8*>(d + (long long)i * 8) = *reinterpret_cast<s16x8*>(o);
}

// ---------------- embedding gather + concat + time-pos + mask -> bf16 ----------------
__global__ __launch_bounds__(256) void embed_k(
    const int* __restrict__ uid, const int* __restrict__ pid, const int* __restrict__ cid,
    const int* __restrict__ gid, const int* __restrict__ tmid, const int* __restrict__ mask,
    const float* __restrict__ ue, const float* __restrict__ pe, const float* __restrict__ ce,
    const float* __restrict__ ge, const float* __restrict__ tp, bf16* __restrict__ xb) {
  int e = blockIdx.x * 256 + threadIdx.x;
  if (e >= NN * ED) return;
  int n = e / ED, j = e - n * ED;
  int mi = mask[n];
  float fm = (float)mi;
  float v;
  if (j < 128)      v = ue[(long long)(uid[n] * mi) * 128 + j];
  else if (j < 256) v = pe[(long long)(pid[n] * mi) * 128 + (j - 128)];
  else if (j < 288) v = ce[(long long)(cid[n] * mi) * 32 + (j - 256)];
  else              v = ge[(long long)(gid[n] * mi) * 64 + (j - 288)];
  v += 0.5f * tp[(long long)(tmid[n] * mi) * ED + j];
  xb[e] = (bf16)(v * fm);
}

// ---------------- gather children: h pair + c fp32 into [m, 3*512] ----------------
__global__ __launch_bounds__(256) void gather_k(
    const bf16* __restrict__ hhi, const bf16* __restrict__ hlo, const float* __restrict__ c,
    bf16* __restrict__ ghi, bf16* __restrict__ glo, float* __restrict__ cch,
    int m, int cbase, int tl) {
  int e = blockIdx.x * 256 + threadIdx.x;
  if (e >= m * 1536) return;
  int r = e / 1536, rem = e - r * 1536;
  int k = rem >> 9, d = rem & 511;
  int t = r / tl, p = r - t * tl;
  long long src = (long long)(cbase + t * 3 * tl + 3 * p + k) * 512 + d;
  ghi[e] = hhi[src];
  glo[e] = hlo[src];
  cch[e] = c[src];
}

// ---------------- forget gates + c_red ----------------
__global__ __launch_bounds__(256) void fcred_k(
    const float* __restrict__ wx, const float* __restrict__ ufh, const float* __restrict__ bf_,
    const float* __restrict__ cch, float* __restrict__ cred, int m) {
  int e = blockIdx.x * 256 + threadIdx.x;
  if (e >= m * 512) return;
  int r = e >> 9, d = e & 511;
  float w = wx[e] + bf_[d];
  long long base = (long long)r * 1536;
  float acc = 0.f;
#pragma unroll
  for (int k = 0; k < 3; ++k) {
    float f = sigmoidf_(w + ufh[base + k * 512 + d]);
    acc += f * cch[base + k * 512 + d];
  }
  cred[e] = acc;
}

// ---------------- iou -> (h,c); h written as hi/lo pair ----------------
__global__ __launch_bounds__(256) void combine_k(
    const float* __restrict__ iou, const float* __restrict__ cred, float* __restrict__ c,
    bf16* __restrict__ hhi, bf16* __restrict__ hlo, int off, int m) {
  int e = blockIdx.x * 256 + threadIdx.x;
  if (e >= m * 512) return;
  int r = e >> 9, d = e & 511;
  long long b = (long long)r * 1536;
  float iv = iou[b + d], ov = iou[b + 512 + d], uv = iou[b + 1024 + d];
  float cr = cred ? cred[e] : 0.f;
  float cn = sigmoidf_(iv) * tanhf(uv) + cr;
  float hn = sigmoidf_(ov) * tanhf(cn);
  long long o = (long long)(off + r) * 512 + d;
  c[o] = cn;
  bf16 hv = (bf16)hn;
  hhi[o] = hv;
  hlo[o] = (bf16)(hn - (float)hv);
}

// ---------------- LayerNorm width 512: LN((ahi+alo) + b)*w + bias -> pair ----------
__global__ __launch_bounds__(256) void ln_k(
    const bf16* __restrict__ ahi, const bf16* __restrict__ alo, const float* __restrict__ b,
    const float* __restrict__ w, const float* __restrict__ bias,
    bf16* __restrict__ ohi, bf16* __restrict__ olo) {
  int r = blockIdx.x, t = threadIdx.x;
  long long base = (long long)r * 512;
  float v0 = (float)ahi[base + t] + (float)alo[base + t] + b[base + t];
  float v1 = (float)ahi[base + 256 + t] + (float)alo[base + 256 + t] + b[base + 256 + t];
  __shared__ float s1[256], s2[256];
  s1[t] = v0 + v1;
  s2[t] = v0 * v0 + v1 * v1;
  __syncthreads();
  for (int s = 128; s > 0; s >>= 1) {
    if (t < s) { s1[t] += s1[t + s]; s2[t] += s2[t + s]; }
    __syncthreads();
  }
  float mu = s1[0] * (1.f / 512.f);
  float var = s2[0] * (1.f / 512.f) - mu * mu;
  float rs = rsqrtf(var + 1e-5f);
  float o0 = (v0 - mu) * rs * w[t] + bias[t];
  float o1 = (v1 - mu) * rs * w[256 + t] + bias[256 + t];
  bf16 h0 = (bf16)o0, h1 = (bf16)o1;
  ohi[base + t] = h0;       olo[base + t] = (bf16)(o0 - (float)h0);
  ohi[base + 256 + t] = h1; olo[base + 256 + t] = (bf16)(o1 - (float)h1);
}

// ---------------- row softmax fp32 -> bf16 padded probs ----------------
__global__ __launch_bounds__(256) void softmax_pb_k(
    const float* __restrict__ sc, bf16* __restrict__ pb, int m, int mpad) {
  long long r = blockIdx.x;
  const float* row = sc + r * m;
  bf16* prow = pb + r * mpad;
  int t = threadIdx.x;
  __shared__ float sh[256];
  float mx = -3.4e38f;
  for (int j = t; j < m; j += 256) mx = fmaxf(mx, row[j]);
  sh[t] = mx;
  __syncthreads();
  for (int s = 128; s > 0; s >>= 1) {
    if (t < s) sh[t] = fmaxf(sh[t], sh[t + s]);
    __syncthreads();
  }
  mx = sh[0];
  __syncthreads();
  float sum = 0.f;
  for (int j = t; j < m; j += 256) sum += expf(row[j] - mx);
  sh[t] = sum;
  __syncthreads();
  for (int s = 128; s > 0; s >>= 1) {
    if (t < s) sh[t] += sh[t + s];
    __syncthreads();
  }
  float inv = 1.f / sh[0];
  for (int j = t; j < mpad; j += 256)
    prow[j] = (j < m) ? (bf16)(expf(row[j] - mx) * inv) : (bf16)0.f;
}

// ---------------- V^T: vt[z][n][k] = V_z[k][n], zero-pad k>=m ----------
__global__ __launch_bounds__(256) void vt_k(const bf16* __restrict__ qkvb,
                                            bf16* __restrict__ vt, int m, int mpad) {
  int total = 6 * 256 * mpad;
  for (int e = blockIdx.x * 256 + threadIdx.x; e < total; e += gridDim.x * 256) {
    int z = e / (256 * mpad);
    int rem = e - z * 256 * mpad;
    int n = rem / mpad, k = rem - n * mpad;
    int b = z >> 1, h = z & 1;
    bf16 v = (bf16)0.f;
    if (k < m) v = qkvb[(long long)(k * 3 + b) * 1536 + 1024 + h * 256 + n];
    vt[e] = v;
  }
}

}  // namespace

extern "C" void kernel_launch(void* const* d_in, const int* in_sizes, int n_in,
                              void* d_out, int out_size, void* d_ws, size_t ws_size,
                              hipStream_t stream) {
  const int* uid  = (const int*)d_in[0];
  const int* pid  = (const int*)d_in[1];
  const int* cid  = (const int*)d_in[2];
  const int* gid  = (const int*)d_in[3];
  const int* tmid = (const int*)d_in[4];
  const int* mask = (const int*)d_in[5];
  const float* ue = (const float*)d_in[6];
  const float* pe = (const float*)d_in[7];
  const float* ce = (const float*)d_in[8];
  const float* ge = (const float*)d_in[9];
  const float* tp = (const float*)d_in[10];
  const float* W_iou = (const float*)d_in[11];
  const float* U_iou = (const float*)d_in[12];
  const float* b_iou = (const float*)d_in[13];
  const float* W_f = (const float*)d_in[14];
  const float* U_f = (const float*)d_in[15];
  const float* b_f = (const float*)d_in[16];
  const float* qkv_w = (const float*)d_in[17];
  const float* qkv_b = (const float*)d_in[18];
  const float* out_w = (const float*)d_in[19];
  const float* out_b = (const float*)d_in[20];
  const float* ln1_w = (const float*)d_in[21];
  const float* ln1_b = (const float*)d_in[22];
  const float* ff1_w = (const float*)d_in[23];
  const float* ff1_b = (const float*)d_in[24];
  const float* ff2_w = (const float*)d_in[25];
  const float* ff2_b = (const float*)d_in[26];
  const float* ln2_w = (const float*)d_in[27];
  const float* ln2_b = (const float*)d_in[28];
  const float* dpw = (const float*)d_in[29];
  const float* dpb = (const float*)d_in[30];
  const float* dcw = (const float*)d_in[31];
  const float* dcb = (const float*)d_in[32];
  const float* dgw = (const float*)d_in[33];
  const float* dgb = (const float*)d_in[34];

  // ---- d_ws (18.4MB): H pair bf16 [5824,512]x2 + decoder weights bf16 ----
  float* ws = (float*)d_ws;
  bf16* Hhi = (bf16*)ws;                     // 2,981,888 el
  bf16* Hlo = Hhi + 2981888LL;               // 2,981,888 el
  bf16* dpwb = (bf16*)(ws + 2981888LL);      // 2,560,000 el
  bf16* dcwb = dpwb + 2560000LL;             // 153,600
  bf16* dgwb = dcwb + 153600LL;              // 524,288

  // ---- d_out scratch (34.77M of 36.83M floats) ----
  float* ob = (float*)d_out;
  float* R1   = ob;                          // 10,077,696: leaf IOU / QKVf / SC / level IOU
  float* R2   = ob + 10077696LL;             // 5,101,056: QKVb / UFH / Pb
  bf16* VT    = (bf16*)(ob + 15178752LL);    // 2,015,232 el
  bf16* ATTOb = (bf16*)(ob + 16186368LL);    // 1,990,656 el
  float* SCR  = ob + 17181696LL;             // 1,990,656: CCH / XB / XCacc
  bf16* XChi  = (bf16*)(ob + 19172352LL);    // 1,990,656 el
  bf16* XClo  = XChi + 1990656LL;
  bf16* RAhi  = (bf16*)(ob + 21163008LL);    // 1,990,656 el
  bf16* RAlo  = RAhi + 1990656LL;
  bf16* RBhi  = (bf16*)(ob + 23153664LL);
  bf16* RBlo  = RBhi + 1990656LL;
  float* WX   = ob + 25144320LL;             // 663,552
  float* CRED = ob + 25807872LL;             // 663,552
  float* Cc   = ob + 26471424LL;             // 2,981,888
  bf16* Xb    = (bf16*)(ob + 29453312LL);    // 2,050,048 el
  bf16* Wb    = (bf16*)(ob + 30478336LL);    // 8,585,216 el -> end 34,770,944 fl

  float* QKVf = R1;
  float* SC   = R1;
  float* IOU  = R1;
  bf16* QKVb  = (bf16*)R2;
  float* UFH  = R2;
  bf16* Pb    = (bf16*)R2;
  float* CCH  = SCR;
  float* XB   = SCR;
  float* XCa  = SCR;

  bf16* W_ioub = Wb;                  // 540,672
  bf16* U_ioub = Wb + 540672LL;       // 2,359,296
  bf16* W_fb   = Wb + 2899968LL;      // 180,224
  bf16* U_fb   = Wb + 3080192LL;      // 2,359,296
  bf16* qkvb   = Wb + 5439488LL;      // 1,572,864
  bf16* outb   = Wb + 7012352LL;      // 524,288
  bf16* ff1b   = Wb + 7536640LL;      // 524,288
  bf16* ff2b   = Wb + 8060928LL;      // 524,288

#define CVT(src, dst, n) cvt8_k<<<((n) / 8 + 255) / 256, 256, 0, stream>>>(src, dst, (n) / 8)
  CVT(W_iou, W_ioub, 540672);
  CVT(U_iou, U_ioub, 2359296);
  CVT(W_f, W_fb, 180224);
  CVT(U_f, U_fb, 2359296);
  CVT(qkv_w, qkvb, 1572864);
  CVT(out_w, outb, 524288);
  CVT(ff1_w, ff1b, 524288);
  CVT(ff2_w, ff2b, 524288);
  CVT(dpw, dpwb, 2560000);
  CVT(dcw, dcwb, 153600);
  CVT(dgw, dgwb, 524288);
#undef CVT

  embed_k<<<(NN * ED + 255) / 256, 256, 0, stream>>>(uid, pid, cid, gid, tmid, mask,
                                                     ue, pe, ce, ge, tp, Xb);

  // leaves
  bgemm(stream, 0, false, Xb, W_ioub, R1, nullptr, nullptr, nullptr,
        3888, 1536, 352, 352, 352, 1536, 1.f);
  combine_k<<<(3888 * 512 + 255) / 256, 256, 0, stream>>>(R1, nullptr, Cc, Hhi, Hlo, 0, 3888);

  static const int OFFL[6] = {5808, 5760, 5616, 5184, 3888, 0};
  int tl = 81;
  for (int l = 4; l >= 0; --l, tl /= 3) {
    int m = 16 * tl;
    int off = OFFL[l];
    int cbase = OFFL[l + 1];
    int T = 3 * m;
    int mpad = (m + 31) & ~31;
    const bf16* xlb = Xb + (long long)off * ED;

    gather_k<<<(m * 1536 + 255) / 256, 256, 0, stream>>>(Hhi, Hlo, Cc, RAhi, RAlo, CCH,
                                                         m, cbase, tl);
    // forget gates: WX = xl@W_f^T ; UFH = h_ch@U_f^T (2-pass split-A)
    bgemm(stream, 0, false, xlb, W_fb, WX, nullptr, nullptr, nullptr,
          m, 512, 352, 352, 352, 512, 1.f);
    bgemm(stream, 0, false, RAhi, U_fb, UFH, nullptr, nullptr, nullptr,
          m, 1536, 1536, 1536, 1536, 1536, 1.f);
    bgemm(stream, 0, true, RAlo, U_fb, UFH, nullptr, UFH, nullptr,
          m, 1536, 1536, 1536, 1536, 1536, 1.f);
    fcred_k<<<(m * 512 + 255) / 256, 256, 0, stream>>>(WX, UFH, b_f, CCH, CRED, m);

    // transformer; current residual pair starts at RA (= gathered h_ch)
    bf16 *curhi = RAhi, *curlo = RAlo, *nxthi = RBhi, *nxtlo = RBlo;
    for (int i = 0; i < 2; ++i) {
      // qkv: pass1 -> QKVf fp32 (+bias), pass2 accum -> QKVb bf16
      bgemm(stream, 0, false, curhi, qkvb + (long long)i * 786432, QKVf, nullptr, nullptr,
            qkv_b + i * 1536, T, 1536, 512, 512, 512, 1536, 1.f);
      bgemm(stream, 1, true, curlo, qkvb + (long long)i * 786432, QKVb, nullptr, QKVf,
            nullptr, T, 1536, 512, 512, 512, 1536, 1.f);
      {
        int total = 6 * 256 * mpad;
        int blocks = (total + 255) / 256; if (blocks > 2048) blocks = 2048;
        vt_k<<<blocks, 256, 0, stream>>>(QKVb, VT, m, mpad);
      }
      bgemm(stream, 0, false, QKVb, QKVb + 512, SC, nullptr, nullptr, nullptr,
            m, m, 256, 4608, 4608, m, 0.0625f,
            6, 1536, 256, 1536, 256, 2LL * m * m, (long long)m * m, 2);
      softmax_pb_k<<<6 * m, 256, 0, stream>>>(SC, Pb, m, mpad);
      bgemm(stream, 1, false, Pb, VT, ATTOb, nullptr, nullptr, nullptr,
            m, 256, mpad, mpad, mpad, 1536, 1.f,
            6, 2LL * m * mpad, (long long)m * mpad, 2LL * 256 * mpad, 256LL * mpad,
            512, 256, 2);
      bgemm(stream, 0, false, ATTOb, outb + (long long)i * 262144, XB, nullptr, nullptr,
            out_b + i * 512, T, 512, 512, 512, 512, 512, 1.f);
      ln_k<<<T, 256, 0, stream>>>(curhi, curlo, XB, ln1_w + i * 512, ln1_b + i * 512,
                                  nxthi, nxtlo);
      // ff1: pass1 -> XCa fp32 (+bias), pass2 accum+relu -> XC pair
      bgemm(stream, 0, false, nxthi, ff1b + (long long)i * 262144, XCa, nullptr, nullptr,
            ff1_b + i * 512, T, 512, 512, 512, 512, 512, 1.f);
      bgemm(stream, 2, true, nxtlo, ff1b + (long long)i * 262144, XChi, XClo, XCa,
            nullptr, T, 512, 512, 512, 512, 512, 1.f);
      // ff2: pass1 -> XB fp32 (+bias), pass2 accum in place
      bgemm(stream, 0, false, XChi, ff2b + (long long)i * 262144, XB, nullptr, nullptr,
            ff2_b + i * 512, T, 512, 512, 512, 512, 512, 1.f);
      bgemm(stream, 0, true, XClo, ff2b + (long long)i * 262144, XB, nullptr, XB,
            nullptr, T, 512, 512, 512, 512, 512, 1.f);
      ln_k<<<T, 256, 0, stream>>>(nxthi, nxtlo, XB, ln2_w + i * 512, ln2_b + i * 512,
                                  curhi, curlo);
    }

    // iou = xl@W_iou^T + b_iou + h_att@U_iou^T (split-A, 2 accum passes)
    bgemm(stream, 0, false, xlb, W_ioub, IOU, nullptr, nullptr, b_iou,
          m, 1536, 352, 352, 352, 1536, 1.f);
    bgemm(stream, 0, true, curhi, U_ioub, IOU, nullptr, IOU, nullptr,
          m, 1536, 1536, 1536, 1536, 1536, 1.f);
    bgemm(stream, 0, true, curlo, U_ioub, IOU, nullptr, IOU, nullptr,
          m, 1536, 1536, 1536, 1536, 1536, 1.f);
    combine_k<<<(m * 512 + 255) / 256, 256, 0, stream>>>(IOU, CRED, Cc, Hhi, Hlo, off, m);
  }

  // decoders: 2-pass split-A from H pair; in-place fp32 accum
  bgemm(stream, 0, false, Hhi, dpwb, ob, nullptr, nullptr, dpb,
        NN, 5000, 512, 512, 512, 5000, 1.f);
  bgemm(stream, 0, true, Hlo, dpwb, ob, nullptr, ob, nullptr,
        NN, 5000, 512, 512, 512, 5000, 1.f);
  bgemm(stream, 0, false, Hhi, dcwb, ob + 29120000LL, nullptr, nullptr, dcb,
        NN, 300, 512, 512, 512, 300, 1.f);
  bgemm(stream, 0, true, Hlo, dcwb, ob + 29120000LL, nullptr, ob + 29120000LL, nullptr,
        NN, 300, 512, 512, 512, 300, 1.f);
  bgemm(stream, 0, false, Hhi, dgwb, ob + 30867200LL, nullptr, nullptr, dgb,
        NN, 1024, 512, 512, 512, 1024, 1.f);
  bgemm(stream, 0, true, Hlo, dgwb, ob + 30867200LL, nullptr, ob + 30867200LL, nullptr,
        NN, 1024, 512, 512, 512, 1024, 1.f);
}

// Round 4
// 2416.803 us; speedup vs baseline: 2.5198x; 1.4451x over previous
//
#include <hip/hip_runtime.h>
#include <hip/hip_bf16.h>

// TreeLSTM forward, round 4: dual-A (hi/lo split-precision) fused MFMA GEMMs,
// merged 3-way decoder, fp32 accumulate everywhere.
// Topology: 16 perfect ternary trees, depth 6; off[l] l=0..5: {5808,5760,5616,5184,3888,0}.

namespace {

constexpr int NN = 5824;
constexpr int ED = 352;

typedef __bf16 bf16;
typedef short s16x8 __attribute__((ext_vector_type(8)));
typedef float f32x4 __attribute__((ext_vector_type(4)));

__device__ __forceinline__ float sigmoidf_(float x) { return 1.f / (1.f + expf(-x)); }

__device__ __forceinline__ void gload_lds16(const void* g, void* s) {
  __builtin_amdgcn_global_load_lds(
      (const __attribute__((address_space(1))) unsigned int*)g,
      (__attribute__((address_space(3))) unsigned int*)s, 16, 0, 0);
}

// ---------------- bf16 MFMA GEMM, optionally dual-A (A_hi + A_lo in one pass) ----------
// C = alpha * (A_hi + A_lo) @ B^T + bias [+Cacc] [relu]
// MODE 0: f32 out, single A           (leaves, W_f, scores, attO)
// MODE 1: f32 out, dual A             (U_f, ff2)
// MODE 2: bf16 out, dual A            (qkv)
// MODE 3: bf16 out, single A          (PV)
// MODE 4: pair out + relu, dual A     (ff1)
// MODE 5: f32 out + accum, dual A     (U_iou)
// MODE 6: decoder region-select out, dual A
template <int MODE>
__global__ __launch_bounds__(256) void bgemm_k(
    const bf16* __restrict__ A, const bf16* __restrict__ Alo, const bf16* __restrict__ B,
    void* __restrict__ Cp, bf16* __restrict__ Clo, const float* __restrict__ Cacc,
    const float* __restrict__ bias, int M, int N, int K, int lda, int ldb, int ldc,
    float alpha, long long sA1, long long sA2, long long sB1, long long sB2,
    long long sC1, long long sC2, int nh) {
  constexpr bool DUAL = (MODE == 1 || MODE == 2 || MODE == 4 || MODE == 5 || MODE == 6);
  const int bz = blockIdx.z;
  const int b1 = bz / nh, b2 = bz - b1 * nh;
  A += (long long)b1 * sA1 + (long long)b2 * sA2;
  if (DUAL) Alo += (long long)b1 * sA1 + (long long)b2 * sA2;
  B += (long long)b1 * sB1 + (long long)b2 * sB2;
  const long long coff = (long long)b1 * sC1 + (long long)b2 * sC2;
  const int bm = blockIdx.y * 128, bn = blockIdx.x * 128;
  __shared__ bf16 As[128 * 32];
  __shared__ bf16 Ls[DUAL ? 128 * 32 : 8];
  __shared__ bf16 Bs[128 * 32];
  const int tid = threadIdx.x;
  const int l = tid & 63;
  const int wr = ((tid >> 7) & 1) * 64;
  const int wc = ((tid >> 6) & 1) * 64;
  f32x4 acc[4][4];
#pragma unroll
  for (int i = 0; i < 4; ++i)
#pragma unroll
    for (int j = 0; j < 4; ++j) acc[i][j] = (f32x4){0.f, 0.f, 0.f, 0.f};

  for (int k0 = 0; k0 < K; k0 += 32) {
#pragma unroll
    for (int r = 0; r < 2; ++r) {
      int idx = r * 256 + tid;
      int row = idx >> 2, cs = idx & 3;
      int cg = cs ^ (row & 3);
      int ra = bm + row; if (ra > M - 1) ra = M - 1;
      int rb = bn + row; if (rb > N - 1) rb = N - 1;
      gload_lds16(A + (long long)ra * lda + k0 + cg * 8, As + idx * 8);
      if (DUAL) gload_lds16(Alo + (long long)ra * lda + k0 + cg * 8, Ls + idx * 8);
      gload_lds16(B + (long long)rb * ldb + k0 + cg * 8, Bs + idx * 8);
    }
    __syncthreads();
    s16x8 af[4], al[4], bfr[4];
#pragma unroll
    for (int mi = 0; mi < 4; ++mi) {
      int row = wr + mi * 16 + (l & 15);
      int ch = ((l >> 4) ^ row) & 3;
      af[mi] = *reinterpret_cast<const s16x8*>(As + row * 32 + ch * 8);
      if (DUAL) al[mi] = *reinterpret_cast<const s16x8*>(Ls + row * 32 + ch * 8);
    }
#pragma unroll
    for (int ni = 0; ni < 4; ++ni) {
      int row = wc + ni * 16 + (l & 15);
      int ch = ((l >> 4) ^ row) & 3;
      bfr[ni] = *reinterpret_cast<const s16x8*>(Bs + row * 32 + ch * 8);
    }
#pragma unroll
    for (int mi = 0; mi < 4; ++mi)
#pragma unroll
      for (int ni = 0; ni < 4; ++ni) {
        acc[mi][ni] =
            __builtin_amdgcn_mfma_f32_16x16x32_bf16(af[mi], bfr[ni], acc[mi][ni], 0, 0, 0);
        if (DUAL)
          acc[mi][ni] =
              __builtin_amdgcn_mfma_f32_16x16x32_bf16(al[mi], bfr[ni], acc[mi][ni], 0, 0, 0);
      }
    __syncthreads();
  }

  const int lc = l & 15, lr4 = (l >> 4) * 4;
#pragma unroll
  for (int mi = 0; mi < 4; ++mi) {
#pragma unroll
    for (int j = 0; j < 4; ++j) {
      int r = bm + wr + mi * 16 + lr4 + j;
      if (r >= M) continue;
#pragma unroll
      for (int ni = 0; ni < 4; ++ni) {
        int c = bn + wc + ni * 16 + lc;
        if (c >= N) continue;
        float v = alpha * acc[mi][ni][j];
        if (bias) v += bias[c];
        long long idx = coff + (long long)r * ldc + c;
        if (MODE == 5) v += Cacc[idx];
        if (MODE == 0 || MODE == 1 || MODE == 5) {
          ((float*)Cp)[idx] = v;
        } else if (MODE == 2 || MODE == 3) {
          ((bf16*)Cp)[idx] = (bf16)v;
        } else if (MODE == 4) {
          v = fmaxf(v, 0.f);
          bf16 hv = (bf16)v;
          ((bf16*)Cp)[idx] = hv;
          Clo[idx] = (bf16)(v - (float)hv);
        } else {  // MODE 6: decoder region select (poi 5000 | cat 300 | coo 1024)
          float* o0 = (float*)Cp;
          if (c < 5000)      o0[(long long)r * 5000 + c] = v;
          else if (c < 5300) o0[29120000LL + (long long)r * 300 + (c - 5000)] = v;
          else               o0[30867200LL + (long long)r * 1024 + (c - 5300)] = v;
        }
      }
    }
  }
}

static void bgemm(hipStream_t st, int mode, const bf16* A, const bf16* Alo, const bf16* B,
                  void* Cp, bf16* Clo, const float* Cacc, const float* bias,
                  int M, int N, int K, int lda, int ldb, int ldc, float alpha,
                  int batches = 1, long long sA1 = 0, long long sA2 = 0, long long sB1 = 0,
                  long long sB2 = 0, long long sC1 = 0, long long sC2 = 0, int nh = 1) {
  dim3 g((N + 127) / 128, (M + 127) / 128, batches), b(256);
#define BGL(MD_)                                                                          \
  bgemm_k<MD_><<<g, b, 0, st>>>(A, Alo, B, Cp, Clo, Cacc, bias, M, N, K, lda, ldb, ldc,   \
                                alpha, sA1, sA2, sB1, sB2, sC1, sC2, nh)
  switch (mode) {
    case 0: BGL(0); break;
    case 1: BGL(1); break;
    case 2: BGL(2); break;
    case 3: BGL(3); break;
    case 4: BGL(4); break;
    case 5: BGL(5); break;
    default: BGL(6); break;
  }
#undef BGL
}

// ---------------- fp32 -> bf16 conversion (n multiple of 8) ----------------
__global__ __launch_bounds__(256) void cvt8_k(const float* __restrict__ s,
                                              bf16* __restrict__ d, int n8) {
  int i = blockIdx.x * 256 + threadIdx.x;
  if (i >= n8) return;
  const float4* p = reinterpret_cast<const float4*>(s + (long long)i * 8);
  float4 a = p[0], b = p[1];
  bf16 o[8] = {(bf16)a.x, (bf16)a.y, (bf16)a.z, (bf16)a.w,
               (bf16)b.x, (bf16)b.y, (bf16)b.z, (bf16)b.w};
  *reinterpret_cast<s16x8*>(d + (long long)i * 8) = *reinterpret_cast<s16x8*>(o);
}

// ---------------- decoder bias concat [6324] ----------------
__global__ __launch_bounds__(256) void biascat_k(const float* __restrict__ p,
                                                 const float* __restrict__ c,
                                                 const float* __restrict__ g,
                                                 float* __restrict__ o) {
  int i = blockIdx.x * 256 + threadIdx.x;
  if (i >= 6324) return;
  o[i] = (i < 5000) ? p[i] : (i < 5300) ? c[i - 5000] : g[i - 5300];
}

// ---------------- embedding gather + concat + time-pos + mask -> bf16 ----------------
__global__ __launch_bounds__(256) void embed_k(
    const int* __restrict__ uid, const int* __restrict__ pid, const int* __restrict__ cid,
    const int* __restrict__ gid, const int* __restrict__ tmid, const int* __restrict__ mask,
    const float* __restrict__ ue, const float* __restrict__ pe, const float* __restrict__ ce,
    const float* __restrict__ ge, const float* __restrict__ tp, bf16* __restrict__ xb) {
  int e = blockIdx.x * 256 + threadIdx.x;
  if (e >= NN * ED) return;
  int n = e / ED, j = e - n * ED;
  int mi = mask[n];
  float fm = (float)mi;
  float v;
  if (j < 128)      v = ue[(long long)(uid[n] * mi) * 128 + j];
  else if (j < 256) v = pe[(long long)(pid[n] * mi) * 128 + (j - 128)];
  else if (j < 288) v = ce[(long long)(cid[n] * mi) * 32 + (j - 256)];
  else              v = ge[(long long)(gid[n] * mi) * 64 + (j - 288)];
  v += 0.5f * tp[(long long)(tmid[n] * mi) * ED + j];
  xb[e] = (bf16)(v * fm);
}

// ---------------- gather children: h pair + c fp32 into [m, 3*512] ----------------
__global__ __launch_bounds__(256) void gather_k(
    const bf16* __restrict__ hhi, const bf16* __restrict__ hlo, const float* __restrict__ c,
    bf16* __restrict__ ghi, bf16* __restrict__ glo, float* __restrict__ cch,
    int m, int cbase, int tl) {
  int e = blockIdx.x * 256 + threadIdx.x;
  if (e >= m * 1536) return;
  int r = e / 1536, rem = e - r * 1536;
  int k = rem >> 9, d = rem & 511;
  int t = r / tl, p = r - t * tl;
  long long src = (long long)(cbase + t * 3 * tl + 3 * p + k) * 512 + d;
  ghi[e] = hhi[src];
  glo[e] = hlo[src];
  cch[e] = c[src];
}

// ---------------- forget gates + c_red ----------------
__global__ __launch_bounds__(256) void fcred_k(
    const float* __restrict__ wx, const float* __restrict__ ufh, const float* __restrict__ bf_,
    const float* __restrict__ cch, float* __restrict__ cred, int m) {
  int e = blockIdx.x * 256 + threadIdx.x;
  if (e >= m * 512) return;
  int r = e >> 9, d = e & 511;
  float w = wx[e] + bf_[d];
  long long base = (long long)r * 1536;
  float acc = 0.f;
#pragma unroll
  for (int k = 0; k < 3; ++k) {
    float f = sigmoidf_(w + ufh[base + k * 512 + d]);
    acc += f * cch[base + k * 512 + d];
  }
  cred[e] = acc;
}

// ---------------- iou -> (h,c); h written as hi/lo pair ----------------
__global__ __launch_bounds__(256) void combine_k(
    const float* __restrict__ iou, const float* __restrict__ cred, float* __restrict__ c,
    bf16* __restrict__ hhi, bf16* __restrict__ hlo, int off, int m) {
  int e = blockIdx.x * 256 + threadIdx.x;
  if (e >= m * 512) return;
  int r = e >> 9, d = e & 511;
  long long b = (long long)r * 1536;
  float iv = iou[b + d], ov = iou[b + 512 + d], uv = iou[b + 1024 + d];
  float cr = cred ? cred[e] : 0.f;
  float cn = sigmoidf_(iv) * tanhf(uv) + cr;
  float hn = sigmoidf_(ov) * tanhf(cn);
  long long o = (long long)(off + r) * 512 + d;
  c[o] = cn;
  bf16 hv = (bf16)hn;
  hhi[o] = hv;
  hlo[o] = (bf16)(hn - (float)hv);
}

// ---------------- LayerNorm width 512: LN((ahi+alo) + b)*w + bias -> pair ----------
__global__ __launch_bounds__(256) void ln_k(
    const bf16* __restrict__ ahi, const bf16* __restrict__ alo, const float* __restrict__ b,
    const float* __restrict__ w, const float* __restrict__ bias,
    bf16* __restrict__ ohi, bf16* __restrict__ olo) {
  int r = blockIdx.x, t = threadIdx.x;
  long long base = (long long)r * 512;
  float v0 = (float)ahi[base + t] + (float)alo[base + t] + b[base + t];
  float v1 = (float)ahi[base + 256 + t] + (float)alo[base + 256 + t] + b[base + 256 + t];
  __shared__ float s1[256], s2[256];
  s1[t] = v0 + v1;
  s2[t] = v0 * v0 + v1 * v1;
  __syncthreads();
  for (int s = 128; s > 0; s >>= 1) {
    if (t < s) { s1[t] += s1[t + s]; s2[t] += s2[t + s]; }
    __syncthreads();
  }
  float mu = s1[0] * (1.f / 512.f);
  float var = s2[0] * (1.f / 512.f) - mu * mu;
  float rs = rsqrtf(var + 1e-5f);
  float o0 = (v0 - mu) * rs * w[t] + bias[t];
  float o1 = (v1 - mu) * rs * w[256 + t] + bias[256 + t];
  bf16 h0 = (bf16)o0, h1 = (bf16)o1;
  ohi[base + t] = h0;       olo[base + t] = (bf16)(o0 - (float)h0);
  ohi[base + 256 + t] = h1; olo[base + 256 + t] = (bf16)(o1 - (float)h1);
}

// ---------------- row softmax fp32 -> bf16 padded probs ----------------
__global__ __launch_bounds__(256) void softmax_pb_k(
    const float* __restrict__ sc, bf16* __restrict__ pb, int m, int mpad) {
  long long r = blockIdx.x;
  const float* row = sc + r * m;
  bf16* prow = pb + r * mpad;
  int t = threadIdx.x;
  __shared__ float sh[256];
  float mx = -3.4e38f;
  for (int j = t; j < m; j += 256) mx = fmaxf(mx, row[j]);
  sh[t] = mx;
  __syncthreads();
  for (int s = 128; s > 0; s >>= 1) {
    if (t < s) sh[t] = fmaxf(sh[t], sh[t + s]);
    __syncthreads();
  }
  mx = sh[0];
  __syncthreads();
  float sum = 0.f;
  for (int j = t; j < m; j += 256) sum += expf(row[j] - mx);
  sh[t] = sum;
  __syncthreads();
  for (int s = 128; s > 0; s >>= 1) {
    if (t < s) sh[t] += sh[t + s];
    __syncthreads();
  }
  float inv = 1.f / sh[0];
  for (int j = t; j < mpad; j += 256)
    prow[j] = (j < m) ? (bf16)(expf(row[j] - mx) * inv) : (bf16)0.f;
}

// ---------------- V^T: vt[z][n][k] = V_z[k][n], zero-pad k>=m ----------
__global__ __launch_bounds__(256) void vt_k(const bf16* __restrict__ qkvb,
                                            bf16* __restrict__ vt, int m, int mpad) {
  int total = 6 * 256 * mpad;
  for (int e = blockIdx.x * 256 + threadIdx.x; e < total; e += gridDim.x * 256) {
    int z = e / (256 * mpad);
    int rem = e - z * 256 * mpad;
    int n = rem / mpad, k = rem - n * mpad;
    int b = z >> 1, h = z & 1;
    bf16 v = (bf16)0.f;
    if (k < m) v = qkvb[(long long)(k * 3 + b) * 1536 + 1024 + h * 256 + n];
    vt[e] = v;
  }
}

}  // namespace

extern "C" void kernel_launch(void* const* d_in, const int* in_sizes, int n_in,
                              void* d_out, int out_size, void* d_ws, size_t ws_size,
                              hipStream_t stream) {
  const int* uid  = (const int*)d_in[0];
  const int* pid  = (const int*)d_in[1];
  const int* cid  = (const int*)d_in[2];
  const int* gid  = (const int*)d_in[3];
  const int* tmid = (const int*)d_in[4];
  const int* mask = (const int*)d_in[5];
  const float* ue = (const float*)d_in[6];
  const float* pe = (const float*)d_in[7];
  const float* ce = (const float*)d_in[8];
  const float* ge = (const float*)d_in[9];
  const float* tp = (const float*)d_in[10];
  const float* W_iou = (const float*)d_in[11];
  const float* U_iou = (const float*)d_in[12];
  const float* b_iou = (const float*)d_in[13];
  const float* W_f = (const float*)d_in[14];
  const float* U_f = (const float*)d_in[15];
  const float* b_f = (const float*)d_in[16];
  const float* qkv_w = (const float*)d_in[17];
  const float* qkv_b = (const float*)d_in[18];
  const float* out_w = (const float*)d_in[19];
  const float* out_b = (const float*)d_in[20];
  const float* ln1_w = (const float*)d_in[21];
  const float* ln1_b = (const float*)d_in[22];
  const float* ff1_w = (const float*)d_in[23];
  const float* ff1_b = (const float*)d_in[24];
  const float* ff2_w = (const float*)d_in[25];
  const float* ff2_b = (const float*)d_in[26];
  const float* ln2_w = (const float*)d_in[27];
  const float* ln2_b = (const float*)d_in[28];
  const float* dpw = (const float*)d_in[29];
  const float* dpb = (const float*)d_in[30];
  const float* dcw = (const float*)d_in[31];
  const float* dcb = (const float*)d_in[32];
  const float* dgw = (const float*)d_in[33];
  const float* dgb = (const float*)d_in[34];

  // ---- d_ws (~18.4MB): H pair + concatenated decoder weights/bias ----
  float* ws = (float*)d_ws;
  bf16* Hhi = (bf16*)ws;                         // 2,981,888 el
  bf16* Hlo = Hhi + 2981888LL;                   // 2,981,888 el
  bf16* dwcat = (bf16*)(ws + 2981888LL);         // 3,237,888 el [6324,512]
  float* bcat = ws + 4600832LL;                  // 6,324 fl

  // ---- d_out scratch (34.77M of 36.83M floats) ----
  float* ob = (float*)d_out;
  float* R1   = ob;                          // 10,077,696: leaf IOU / SC / level IOU
  float* PQ   = ob + 10077696LL;             // 5,101,056: QKVb / UFH / Pb (time-disjoint)
  bf16* VT    = (bf16*)(ob + 15178752LL);    // 2,015,232 el
  bf16* ATTOb = (bf16*)(ob + 16186368LL);    // 1,990,656 el
  float* SCR  = ob + 17181696LL;             // 1,990,656: CCH / XB
  bf16* XChi  = (bf16*)(ob + 19172352LL);    // 1,990,656 el
  bf16* XClo  = XChi + 1990656LL;
  bf16* RAhi  = (bf16*)(ob + 21163008LL);    // 1,990,656 el
  bf16* RAlo  = RAhi + 1990656LL;
  bf16* RBhi  = (bf16*)(ob + 23153664LL);
  bf16* RBlo  = RBhi + 1990656LL;
  float* WX   = ob + 25144320LL;             // 663,552
  float* CRED = ob + 25807872LL;             // 663,552
  float* Cc   = ob + 26471424LL;             // 2,981,888
  bf16* Xb    = (bf16*)(ob + 29453312LL);    // 2,050,048 el
  bf16* Wb    = (bf16*)(ob + 30478336LL);    // 8,585,216 el -> end 34,770,944 fl

  float* SC   = R1;
  float* IOU  = R1;
  bf16* QKVb  = (bf16*)PQ;
  float* UFH  = PQ;
  bf16* Pb    = (bf16*)PQ;
  float* CCH  = SCR;
  float* XB   = SCR;

  bf16* W_ioub = Wb;                  // 540,672
  bf16* U_ioub = Wb + 540672LL;       // 2,359,296
  bf16* W_fb   = Wb + 2899968LL;      // 180,224
  bf16* U_fb   = Wb + 3080192LL;      // 2,359,296
  bf16* qkvb   = Wb + 5439488LL;      // 1,572,864
  bf16* outb   = Wb + 7012352LL;      // 524,288
  bf16* ff1b   = Wb + 7536640LL;      // 524,288
  bf16* ff2b   = Wb + 8060928LL;      // 524,288

#define CVT(src, dst, n) cvt8_k<<<((n) / 8 + 255) / 256, 256, 0, stream>>>(src, dst, (n) / 8)
  CVT(W_iou, W_ioub, 540672);
  CVT(U_iou, U_ioub, 2359296);
  CVT(W_f, W_fb, 180224);
  CVT(U_f, U_fb, 2359296);
  CVT(qkv_w, qkvb, 1572864);
  CVT(out_w, outb, 524288);
  CVT(ff1_w, ff1b, 524288);
  CVT(ff2_w, ff2b, 524288);
  CVT(dpw, dwcat, 2560000);
  CVT(dcw, dwcat + 2560000LL, 153600);
  CVT(dgw, dwcat + 2713600LL, 524288);
#undef CVT
  biascat_k<<<25, 256, 0, stream>>>(dpb, dcb, dgb, bcat);

  embed_k<<<(NN * ED + 255) / 256, 256, 0, stream>>>(uid, pid, cid, gid, tmid, mask,
                                                     ue, pe, ce, ge, tp, Xb);

  // leaves
  bgemm(stream, 0, Xb, nullptr, W_ioub, R1, nullptr, nullptr, nullptr,
        3888, 1536, 352, 352, 352, 1536, 1.f);
  combine_k<<<(3888 * 512 + 255) / 256, 256, 0, stream>>>(R1, nullptr, Cc, Hhi, Hlo, 0, 3888);

  static const int OFFL[6] = {5808, 5760, 5616, 5184, 3888, 0};
  int tl = 81;
  for (int l = 4; l >= 0; --l, tl /= 3) {
    int m = 16 * tl;
    int off = OFFL[l];
    int cbase = OFFL[l + 1];
    int T = 3 * m;
    int mpad = (m + 31) & ~31;
    const bf16* xlb = Xb + (long long)off * ED;

    gather_k<<<(m * 1536 + 255) / 256, 256, 0, stream>>>(Hhi, Hlo, Cc, RAhi, RAlo, CCH,
                                                         m, cbase, tl);
    bgemm(stream, 0, xlb, nullptr, W_fb, WX, nullptr, nullptr, nullptr,
          m, 512, 352, 352, 352, 512, 1.f);
    bgemm(stream, 1, RAhi, RAlo, U_fb, UFH, nullptr, nullptr, nullptr,
          m, 1536, 1536, 1536, 1536, 1536, 1.f);
    fcred_k<<<(m * 512 + 255) / 256, 256, 0, stream>>>(WX, UFH, b_f, CCH, CRED, m);

    bf16 *curhi = RAhi, *curlo = RAlo, *nxthi = RBhi, *nxtlo = RBlo;
    for (int i = 0; i < 2; ++i) {
      bgemm(stream, 2, curhi, curlo, qkvb + (long long)i * 786432, QKVb, nullptr, nullptr,
            qkv_b + i * 1536, T, 1536, 512, 512, 512, 1536, 1.f);
      {
        int total = 6 * 256 * mpad;
        int blocks = (total + 255) / 256; if (blocks > 2048) blocks = 2048;
        vt_k<<<blocks, 256, 0, stream>>>(QKVb, VT, m, mpad);
      }
      bgemm(stream, 0, QKVb, nullptr, QKVb + 512, SC, nullptr, nullptr, nullptr,
            m, m, 256, 4608, 4608, m, 0.0625f,
            6, 1536, 256, 1536, 256, 2LL * m * m, (long long)m * m, 2);
      softmax_pb_k<<<6 * m, 256, 0, stream>>>(SC, Pb, m, mpad);
      bgemm(stream, 3, Pb, nullptr, VT, ATTOb, nullptr, nullptr, nullptr,
            m, 256, mpad, mpad, mpad, 1536, 1.f,
            6, 2LL * m * mpad, (long long)m * mpad, 2LL * 256 * mpad, 256LL * mpad,
            512, 256, 2);
      bgemm(stream, 0, ATTOb, nullptr, outb + (long long)i * 262144, XB, nullptr, nullptr,
            out_b + i * 512, T, 512, 512, 512, 512, 512, 1.f);
      ln_k<<<T, 256, 0, stream>>>(curhi, curlo, XB, ln1_w + i * 512, ln1_b + i * 512,
                                  nxthi, nxtlo);
      bgemm(stream, 4, nxthi, nxtlo, ff1b + (long long)i * 262144, XChi, XClo, nullptr,
            ff1_b + i * 512, T, 512, 512, 512, 512, 512, 1.f);
      bgemm(stream, 1, XChi, XClo, ff2b + (long long)i * 262144, XB, nullptr, nullptr,
            ff2_b + i * 512, T, 512, 512, 512, 512, 512, 1.f);
      ln_k<<<T, 256, 0, stream>>>(nxthi, nxtlo, XB, ln2_w + i * 512, ln2_b + i * 512,
                                  curhi, curlo);
    }

    bgemm(stream, 0, xlb, nullptr, W_ioub, IOU, nullptr, nullptr, b_iou,
          m, 1536, 352, 352, 352, 1536, 1.f);
    bgemm(stream, 5, curhi, curlo, U_ioub, IOU, nullptr, IOU, nullptr,
          m, 1536, 1536, 1536, 1536, 1536, 1.f);
    combine_k<<<(m * 512 + 255) / 256, 256, 0, stream>>>(IOU, CRED, Cc, Hhi, Hlo, off, m);
  }

  // merged decoders: [5824, 6324] -> region-select write covering all of d_out
  bgemm(stream, 6, Hhi, Hlo, dwcat, ob, nullptr, nullptr, bcat,
        NN, 6324, 512, 512, 512, 0, 1.f);
}